// Round 2
// 288.395 us; speedup vs baseline: 1.1694x; 1.1694x over previous
//
#include <hip/hip_runtime.h>
#include <hip/hip_bf16.h>
#include <math.h>
#include <stdint.h>

// ---------------------------------------------------------------------------
// AttentionLayer B=2,S=2048,D=1024,H=16,Hd=64.  fp32 or bf16 in/out, sniffed
// at runtime.  Pipeline: sniff -> convert (fp32->bf16 materialization) ->
// gemm_qkv (m97-structure MFMA, global_load_lds) -> flash -> gemm_o.
// R11 (= R10 resubmit after container flake, + 3-tier scratch plan):
// GEMMs use the m97 structure: one-time bf16 conversion pass, then 128x128
// tile / BK=32 / linear LDS / global_load_lds width-16 for both operands.
// Scratch tiers by ws_size: FULL = everything in ws (no d_out aliasing);
// MID  = qc->dead AO region, kc/vc->dead d_out, weights in ws;
// MIN  = B reg-staged (no converted weights), qc->AO, kc/vc->d_out.
// Flash unchanged this round (isolate the GEMM change).
// ---------------------------------------------------------------------------

typedef __bf16 bf16x8 __attribute__((ext_vector_type(8)));
typedef float  f32x4  __attribute__((ext_vector_type(4)));
typedef float  f32x8  __attribute__((ext_vector_type(8)));
typedef unsigned short u16x8 __attribute__((ext_vector_type(8)));
typedef u16x8 u16x8a __attribute__((may_alias));
typedef f32x8 f32x8a __attribute__((may_alias));
typedef unsigned short u16a __attribute__((may_alias));
typedef float f32a __attribute__((may_alias));

#define BATCH 2
#define SQL   2048
#define DM    1024
#define NH    16
#define HD    64

__device__ __forceinline__ unsigned short f2bf(float f) {
    union { __hip_bfloat16 h; unsigned short u; } cv;
    cv.h = __float2bfloat16(f);
    return cv.u;
}
__device__ __forceinline__ float bf2f(unsigned short u) {
    union { unsigned int i; float f; } cv;
    cv.i = ((unsigned int)u) << 16;
    return cv.f;
}
__device__ __forceinline__ bf16x8 ldfrag(const unsigned short* p) {
    return __builtin_bit_cast(bf16x8, *(const u16x8a*)p);
}
// Stage 8 contiguous elements (fp32->bf16 or bf16 passthrough) into LDS.
__device__ __forceinline__ void stage8(const void* __restrict__ src, size_t off,
                                       int f32f, unsigned short* dst) {
    if (f32f) {
        f32x8 v = *(const f32x8a*)((const float*)src + off);
        u16x8 o;
#pragma unroll
        for (int i = 0; i < 8; i++) o[i] = f2bf(v[i]);
        *(u16x8a*)dst = o;
    } else {
        *(u16x8a*)dst = *(const u16x8a*)((const unsigned short*)src + off);
    }
}
__device__ __forceinline__ float rdel(const void* p, size_t i, int f) {
    return f ? ((const f32a*)p)[i] : bf2f(((const u16a*)p)[i]);
}
// Async global->LDS, 16 B per lane.  LDS dst is wave-uniform base +
// lane*16 (HW rule); global src is per-lane.
__device__ __forceinline__ void gload16(const void* g, void* l) {
    __builtin_amdgcn_global_load_lds(
        (const __attribute__((address_space(1))) unsigned int*)g,
        (__attribute__((address_space(3))) unsigned int*)l,
        16, 0, 0);
}

// ---------------------------------------------------------------------------
// Dtype sniffer: flag = 1 -> fp32 inputs (and fp32 output).
// ---------------------------------------------------------------------------
__global__ void sniff(const void* __restrict__ q, int* __restrict__ flag) {
    __shared__ int cnt;
    if (threadIdx.x == 0) cnt = 0;
    __syncthreads();
    const u16a* p = (const u16a*)q;
    int c = 0;
#pragma unroll
    for (int i = 0; i < 8; i++) {
        unsigned short u = p[threadIdx.x * 8 + i];
        int e = (u >> 7) & 0xFF;
        if (e >= 96 && e <= 159) c++;
    }
    atomicAdd(&cnt, c);
    __syncthreads();
    if (threadIdx.x == 0) *flag = (cnt < 1741) ? 1 : 0;   // 85% of 2048
}

// ---------------------------------------------------------------------------
// Convert pass: fp32 -> bf16 (RN, same rounding as the inline conversion the
// validated R9 kernel used).  z 0..2: activations (4M elems each), z 3..6:
// weights (1M each; only launched when converted weights are wanted).
// No-op when inputs are already bf16 (flag==0).
// ---------------------------------------------------------------------------
__global__ __launch_bounds__(256)
void convert(const void* s0, const void* s1, const void* s2, const void* s3,
             const void* s4, const void* s5, const void* s6,
             unsigned short* d0, unsigned short* d1, unsigned short* d2,
             unsigned short* d3, unsigned short* d4, unsigned short* d5,
             unsigned short* d6, const int* __restrict__ flag)
{
    if (*flag == 0) return;
    const int z = blockIdx.z;
    const float* s; unsigned short* d; size_t n;
    switch (z) {
        case 0: s = (const float*)s0; d = d0; n = (size_t)BATCH * SQL * DM; break;
        case 1: s = (const float*)s1; d = d1; n = (size_t)BATCH * SQL * DM; break;
        case 2: s = (const float*)s2; d = d2; n = (size_t)BATCH * SQL * DM; break;
        case 3: s = (const float*)s3; d = d3; n = (size_t)DM * DM; break;
        case 4: s = (const float*)s4; d = d4; n = (size_t)DM * DM; break;
        case 5: s = (const float*)s5; d = d5; n = (size_t)DM * DM; break;
        default: s = (const float*)s6; d = d6; n = (size_t)DM * DM; break;
    }
    const size_t stride = (size_t)gridDim.x * blockDim.x * 8;
    for (size_t i = ((size_t)blockIdx.x * blockDim.x + threadIdx.x) * 8; i < n;
         i += stride) {
        f32x8 v = *(const f32x8a*)(s + i);
        u16x8 o;
#pragma unroll
        for (int j = 0; j < 8; j++) o[j] = f2bf(v[j]);
        *(u16x8a*)(d + i) = o;
    }
}

// ---------------------------------------------------------------------------
// GEMM core (m97 structure): C[M,N] = A[M,K] @ Bt[N,K]^T + bias.
// K=N=1024, bf16 MFMA 16x16x32, 128x128 tile, BK=32, 256 threads (4 waves
// 2x2), 4x4 MFMA per wave.  A always staged via global_load_lds (bf16
// source).  B via global_load_lds (BLDS=1, bf16 source) or reg-staged with
// runtime dtype (BLDS=0 fallback when ws has no room for converted W).
// LDS linear [128][32] u16 (global_load_lds requires contiguous dst).
// ---------------------------------------------------------------------------
template<int BLDS>
__device__ __forceinline__ void gemm_core(
    const unsigned short* __restrict__ Abf,
    const unsigned short* __restrict__ Bbf,   // bf16 B (used when BLDS)
    const void* __restrict__ Braw,            // raw B, dtype wF32 (BLDS=0)
    const void* __restrict__ bias, void* __restrict__ Cv,
    float scale, int wF32, int oF32, int bF32)
{
    constexpr int K = 1024, N = 1024, BK = 32;
    __shared__ unsigned short Alds[128 * BK];
    __shared__ unsigned short Blds[128 * BK];

    const int t = threadIdx.x;
    const int lane = t & 63, wave = t >> 6;
    const int quad = lane >> 4, r15 = lane & 15;
    const int wm = (wave >> 1) * 64, wn = (wave & 1) * 64;
    const int m0 = blockIdx.x * 128, n0 = blockIdx.y * 128;

    f32x4 acc[4][4];
#pragma unroll
    for (int i = 0; i < 4; i++)
#pragma unroll
        for (int j = 0; j < 4; j++) acc[i][j] = (f32x4){0.f, 0.f, 0.f, 0.f};

    // global_load_lds geometry: wave w stages 32 rows (2 calls x 16 rows);
    // lane l covers row base+l/4, 16-byte chunk l%4.  LDS dst = wave-uniform
    // base + lane*16 lands exactly on linear [row][32 u16] layout.
    const int gr = lane >> 2, gc = lane & 3;
    const unsigned short* gA = Abf + (size_t)(m0 + wave * 32 + gr) * K + gc * 8;
    const unsigned short* gB = Bbf + (size_t)(n0 + wave * 32 + gr) * K + gc * 8;
    unsigned short* lA = &Alds[wave * 1024];
    unsigned short* lB = &Blds[wave * 1024];
    // BLDS=0 staging indices
    const int srow = t >> 2, sch = t & 3;
    const size_t offB0 = (size_t)(n0 + srow) * K + sch * 8;
    const size_t offB1 = (size_t)(n0 + 64 + srow) * K + sch * 8;

    for (int k0 = 0; k0 < K; k0 += BK) {
        gload16(gA + k0, lA);
        gload16(gA + k0 + 16 * K, lA + 512);
        if constexpr (BLDS) {
            gload16(gB + k0, lB);
            gload16(gB + k0 + 16 * K, lB + 512);
        } else {
            stage8(Braw, offB0 + k0, wF32, &Blds[srow * BK + sch * 8]);
            stage8(Braw, offB1 + k0, wF32, &Blds[(64 + srow) * BK + sch * 8]);
        }
        __syncthreads();

        bf16x8 af[4], bfr[4];
#pragma unroll
        for (int i = 0; i < 4; i++)
            af[i] = ldfrag(&Alds[(wm + i * 16 + r15) * BK + quad * 8]);
#pragma unroll
        for (int j = 0; j < 4; j++)
            bfr[j] = ldfrag(&Blds[(wn + j * 16 + r15) * BK + quad * 8]);
#pragma unroll
        for (int i = 0; i < 4; i++)
#pragma unroll
            for (int j = 0; j < 4; j++)
                acc[i][j] = __builtin_amdgcn_mfma_f32_16x16x32_bf16(af[i], bfr[j], acc[i][j], 0, 0, 0);
        __syncthreads();
    }

    float bvv[4];
#pragma unroll
    for (int j = 0; j < 4; j++)
        bvv[j] = rdel(bias, n0 + wn + j * 16 + r15, bF32);

#pragma unroll
    for (int i = 0; i < 4; i++)
#pragma unroll
        for (int j = 0; j < 4; j++)
#pragma unroll
            for (int r = 0; r < 4; r++) {
                int rr = m0 + wm + i * 16 + quad * 4 + r;
                int cc = n0 + wn + j * 16 + r15;
                float vv = (acc[i][j][r] + bvv[j]) * scale;
                if (oF32) ((f32a*)Cv)[(size_t)rr * N + cc] = vv;
                else      ((u16a*)Cv)[(size_t)rr * N + cc] = f2bf(vv);
            }
}

template<int BLDS>
__global__ __launch_bounds__(256)
void gemm_qkv_k(const void* __restrict__ xq, const void* __restrict__ xk,
                const void* __restrict__ xv,
                const unsigned short* __restrict__ qc,
                const unsigned short* __restrict__ kc,
                const unsigned short* __restrict__ vc,
                const void* __restrict__ Wq, const void* __restrict__ Wk,
                const void* __restrict__ Wv,
                const unsigned short* __restrict__ Wqc,
                const unsigned short* __restrict__ Wkc,
                const unsigned short* __restrict__ Wvc,
                const void* __restrict__ bq, const void* __restrict__ bk,
                const void* __restrict__ bv,
                unsigned short* __restrict__ Qp, unsigned short* __restrict__ Kp,
                unsigned short* __restrict__ Vp,
                float qscale, const int* __restrict__ flag)
{
    const int f = *flag;
    const int z = blockIdx.z;
    const void* xo = (z == 0) ? xq : (z == 1) ? xk : xv;
    const unsigned short* xc = (z == 0) ? qc : (z == 1) ? kc : vc;
    const unsigned short* A = f ? xc : (const unsigned short*)xo;
    const void* Wraw = (z == 0) ? Wq : (z == 1) ? Wk : Wv;
    const unsigned short* Wc = (z == 0) ? Wqc : (z == 1) ? Wkc : Wvc;
    const unsigned short* Bc = (BLDS && f) ? Wc : (const unsigned short*)Wraw;
    const void* bi = (z == 0) ? bq : (z == 1) ? bk : bv;
    unsigned short* C = (z == 0) ? Qp : (z == 1) ? Kp : Vp;
    gemm_core<BLDS>(A, Bc, Wraw, bi, C, (z == 0) ? qscale : 1.0f, f, 0, f);
}

template<int BLDS>
__global__ __launch_bounds__(256)
void gemm_o_k(const unsigned short* __restrict__ A, const void* __restrict__ Wo,
              const unsigned short* __restrict__ Woc, const void* __restrict__ bo,
              void* __restrict__ out, const int* __restrict__ flag)
{
    const int f = *flag;
    const unsigned short* Bc = (BLDS && f) ? Woc : (const unsigned short*)Wo;
    gemm_core<BLDS>(A, Bc, Wo, bo, out, 1.0f, f, f, f);
}

// ---------------------------------------------------------------------------
// Flash attention, maxless softmax (unchanged this round).  Grid (32
// q-tiles, 32 b*h), 4 waves; each wave owns 16 Q rows.  Scores in log2
// domain (Q pre-scaled by 0.125*log2e).  All LDS rows stride 72 u16.
// ---------------------------------------------------------------------------
__global__ __launch_bounds__(256)
void flash(const unsigned short* __restrict__ Qp,
           const unsigned short* __restrict__ Kp,
           const unsigned short* __restrict__ Vp,
           const int* __restrict__ mask,
           unsigned short* __restrict__ AO)
{
    __shared__ unsigned short Klds[64 * 72];      // [key][d]
    __shared__ unsigned short Vt[64 * 72];        // [d][key]
    __shared__ unsigned short Plds[4][16 * 72];   // per-wave P

    const int t = threadIdx.x, wave = t >> 6, lane = t & 63;
    const int quad = lane >> 4, r15 = lane & 15;
    const int qt = blockIdx.x, bh = blockIdx.y, b = bh >> 4, h = bh & 15;
    const size_t base = (size_t)b * SQL * DM + (size_t)h * HD;

    const int qrow = qt * 64 + wave * 16 + r15;
    const bf16x8 qf0 = ldfrag(&Qp[base + (size_t)qrow * DM + quad * 8]);
    const bf16x8 qf1 = ldfrag(&Qp[base + (size_t)qrow * DM + 32 + quad * 8]);

    f32x4 o[4];
#pragma unroll
    for (int jd = 0; jd < 4; jd++) o[jd] = (f32x4){0.f, 0.f, 0.f, 0.f};
    float l_i[4] = {0.f, 0.f, 0.f, 0.f};

    const int krow = t >> 3, kch = t & 7;

    for (int n0 = 0; n0 < SQL; n0 += 64) {
        // ---- stage K [64 keys][64 d], padded rows ----
#pragma unroll
        for (int i = 0; i < 2; i++) {
            int row = i * 32 + krow;
            *(u16x8a*)&Klds[row * 72 + kch * 8] =
                *(const u16x8a*)&Kp[base + (size_t)(n0 + row) * DM + kch * 8];
        }
        // ---- stage V transposed: Vt[d][key] ----
#pragma unroll
        for (int i = 0; i < 2; i++) {
            int c8 = i * 4 + wave;
            u16x8 v8 = *(const u16x8a*)&Vp[base + (size_t)(n0 + lane) * DM + c8 * 8];
#pragma unroll
            for (int jj = 0; jj < 8; jj++) Vt[(c8 * 8 + jj) * 72 + lane] = v8[jj];
        }
        __syncthreads();

        // ---- S = Q K^T (log2-scaled) ----
        f32x4 s4[4];
#pragma unroll
        for (int j = 0; j < 4; j++) s4[j] = (f32x4){0.f, 0.f, 0.f, 0.f};
#pragma unroll
        for (int j = 0; j < 4; j++) {
            bf16x8 kf0 = ldfrag(&Klds[(j * 16 + r15) * 72 + quad * 8]);
            bf16x8 kf1 = ldfrag(&Klds[(j * 16 + r15) * 72 + 32 + quad * 8]);
            s4[j] = __builtin_amdgcn_mfma_f32_16x16x32_bf16(qf0, kf0, s4[j], 0, 0, 0);
            s4[j] = __builtin_amdgcn_mfma_f32_16x16x32_bf16(qf1, kf1, s4[j], 0, 0, 0);
        }
        // ---- maxless softmax: p = exp2(s) ----
#pragma unroll
        for (int j = 0; j < 4; j++) {
            const float mval = (mask[b * SQL + n0 + j * 16 + r15] != 0)
                                   ? -INFINITY : 0.f;
#pragma unroll
            for (int r = 0; r < 4; r++) {
                float p = exp2f(s4[j][r] + mval);
                l_i[r] += p;
                Plds[wave][(quad * 4 + r) * 72 + j * 16 + r15] = f2bf(p);
            }
        }
        asm volatile("" ::: "memory");

        // ---- O += P @ V ----
#pragma unroll
        for (int kf = 0; kf < 2; kf++) {
            bf16x8 pa = ldfrag(&Plds[wave][r15 * 72 + kf * 32 + quad * 8]);
#pragma unroll
            for (int jd = 0; jd < 4; jd++) {
                bf16x8 vb8 = ldfrag(&Vt[(jd * 16 + r15) * 72 + kf * 32 + quad * 8]);
                o[jd] = __builtin_amdgcn_mfma_f32_16x16x32_bf16(pa, vb8, o[jd], 0, 0, 0);
            }
        }
        __syncthreads();
    }

#pragma unroll
    for (int off = 1; off < 16; off <<= 1)
#pragma unroll
        for (int r = 0; r < 4; r++) l_i[r] += __shfl_xor(l_i[r], off, 64);
#pragma unroll
    for (int r = 0; r < 4; r++) l_i[r] = (l_i[r] > 0.f) ? 1.0f / l_i[r] : 0.f;

#pragma unroll
    for (int jd = 0; jd < 4; jd++)
#pragma unroll
        for (int r = 0; r < 4; r++) {
            int row = qt * 64 + wave * 16 + quad * 4 + r;
            AO[base + (size_t)row * DM + jd * 16 + r15] = f2bf(o[jd][r] * l_i[r]);
        }
}

// ---------------------------------------------------------------------------
extern "C" void kernel_launch(void* const* d_in, const int* in_sizes, int n_in,
                              void* d_out, int out_size, void* d_ws, size_t ws_size,
                              hipStream_t stream)
{
    (void)in_sizes; (void)n_in; (void)out_size;

    const void* q    = d_in[0];
    const void* k    = d_in[1];
    const void* v    = d_in[2];
    const int*  mask = (const int*)d_in[3];
    const void* Wq   = d_in[4];
    const void* bq   = d_in[5];
    const void* Wk   = d_in[6];
    const void* bk   = d_in[7];
    const void* Wv   = d_in[8];
    const void* bv   = d_in[9];
    const void* Wo   = d_in[10];
    const void* bo   = d_in[11];

    const size_t ACT = (size_t)BATCH * SQL * DM;   // 4M elems (8 MB bf16)
    const size_t WE  = (size_t)DM * DM;            // 1M elems (2 MB bf16)
    int* flag = (int*)d_ws;                        // 512 B header
    unsigned short* Qp = (unsigned short*)((char*)d_ws + 512);
    unsigned short* Kp = Qp + ACT;
    unsigned short* Vp = Kp + ACT;
    unsigned short* AO = Vp + ACT;                 // 32 MB + 512 B baseline

    // Scratch tiers (host-side, from ws_size):
    //   FULL: everything in ws; d_out untouched until gemm_o.
    //   MID : qc aliases dead AO region, kc/vc alias dead d_out (16 MB in
    //         fp32 mode -- and convert only writes in fp32 mode), W in ws.
    //   MIN : like MID but no converted weights; B reg-staged (BLDS=0).
    const size_t needFull = 512 + (4 * ACT + 3 * ACT + 4 * WE) * 2;
    const size_t needMid  = 512 + (4 * ACT + 4 * WE) * 2;
    const int tier = (ws_size >= needFull) ? 2 : (ws_size >= needMid) ? 1 : 0;

    unsigned short* qc;
    unsigned short* kc;
    unsigned short* vc;
    unsigned short* Wqc = AO + ACT;                // ws past baseline
    unsigned short* Wkc = Wqc + WE;
    unsigned short* Wvc = Wkc + WE;
    unsigned short* Woc = Wvc + WE;
    if (tier == 2) {
        qc = Woc + WE;
        kc = qc + ACT;
        vc = kc + ACT;
    } else {
        qc = AO;                                   // dead until flash writes
        kc = (unsigned short*)d_out;               // dead until gemm_o writes
        vc = kc + ACT;
    }

    // Fold 1/sqrt(64) and log2(e) into Q so flash uses exp2 directly.
    const float QSCALE = 0.125f * 1.44269504088896340736f;

    sniff<<<1, 256, 0, stream>>>(q, flag);
    if (tier >= 1) {
        convert<<<dim3(256, 1, 7), 256, 0, stream>>>(
            q, k, v, Wq, Wk, Wv, Wo, qc, kc, vc, Wqc, Wkc, Wvc, Woc, flag);
        gemm_qkv_k<1><<<dim3(32, 8, 3), 256, 0, stream>>>(
            q, k, v, qc, kc, vc, Wq, Wk, Wv, Wqc, Wkc, Wvc,
            bq, bk, bv, Qp, Kp, Vp, QSCALE, flag);
    } else {
        convert<<<dim3(256, 1, 3), 256, 0, stream>>>(
            q, k, v, nullptr, nullptr, nullptr, nullptr,
            qc, kc, vc, nullptr, nullptr, nullptr, nullptr, flag);
        gemm_qkv_k<0><<<dim3(32, 8, 3), 256, 0, stream>>>(
            q, k, v, qc, kc, vc, Wq, Wk, Wv, nullptr, nullptr, nullptr,
            bq, bk, bv, Qp, Kp, Vp, QSCALE, flag);
    }
    flash<<<dim3(SQL / 64, BATCH * NH), 256, 0, stream>>>(Qp, Kp, Vp, mask, AO);
    if (tier >= 1)
        gemm_o_k<1><<<dim3(32, 8), 256, 0, stream>>>(AO, Wo, Woc, bo, d_out, flag);
    else
        gemm_o_k<0><<<dim3(32, 8), 256, 0, stream>>>(AO, Wo, nullptr, bo, d_out, flag);
}

// Round 3
// 283.032 us; speedup vs baseline: 1.1916x; 1.0190x over previous
//
#include <hip/hip_runtime.h>
#include <hip/hip_bf16.h>
#include <math.h>
#include <stdint.h>

// ---------------------------------------------------------------------------
// AttentionLayer B=2,S=2048,D=1024,H=16,Hd=64.  fp32 or bf16 in/out, sniffed
// at runtime.  Pipeline: sniff -> convert -> gemm_qkv -> flash -> gemm_o.
// R12: flash restructured.
//  * V-GEMM (z=2) epilogue writes VT[b][h][d][tok] directly (4 acc rows are
//    contiguous toks -> packed b64 stores), killing flash's per-tile scalar
//    V transpose (16 ds_write_b16/thread/tile, redone 32x redundantly).
//  * flash stages K and V tiles via global_load_lds width-16 into linear
//    [row][64] LDS with both-sides XOR chunk swizzle (slot = c ^ (row&7)):
//    inverse-permuted per-lane global source + XOR'd read address (rule 21).
//    Linear 128B rows would be a 16-way phase conflict; swizzled = 2-way.
//  * 2-phase async: double-buffered K/V LDS, next-tile loads issued before
//    current tile's QK/softmax/PV, single __syncthreads per tile (compiler
//    emits the vmcnt(0) drain at the barrier = T3 minimum recipe).
// GEMMs keep the R11 m97 structure (128x128, BK=32, global_load_lds).
// ---------------------------------------------------------------------------

typedef __bf16 bf16x8 __attribute__((ext_vector_type(8)));
typedef float  f32x4  __attribute__((ext_vector_type(4)));
typedef float  f32x8  __attribute__((ext_vector_type(8)));
typedef unsigned short u16x8 __attribute__((ext_vector_type(8)));
typedef unsigned short u16x4 __attribute__((ext_vector_type(4)));
typedef u16x8 u16x8a __attribute__((may_alias));
typedef u16x4 u16x4a __attribute__((may_alias));
typedef f32x8 f32x8a __attribute__((may_alias));
typedef unsigned short u16a __attribute__((may_alias));
typedef float f32a __attribute__((may_alias));

#define BATCH 2
#define SQL   2048
#define DM    1024
#define NH    16
#define HD    64

__device__ __forceinline__ unsigned short f2bf(float f) {
    union { __hip_bfloat16 h; unsigned short u; } cv;
    cv.h = __float2bfloat16(f);
    return cv.u;
}
__device__ __forceinline__ float bf2f(unsigned short u) {
    union { unsigned int i; float f; } cv;
    cv.i = ((unsigned int)u) << 16;
    return cv.f;
}
__device__ __forceinline__ bf16x8 ldfrag(const unsigned short* p) {
    return __builtin_bit_cast(bf16x8, *(const u16x8a*)p);
}
__device__ __forceinline__ void stage8(const void* __restrict__ src, size_t off,
                                       int f32f, unsigned short* dst) {
    if (f32f) {
        f32x8 v = *(const f32x8a*)((const float*)src + off);
        u16x8 o;
#pragma unroll
        for (int i = 0; i < 8; i++) o[i] = f2bf(v[i]);
        *(u16x8a*)dst = o;
    } else {
        *(u16x8a*)dst = *(const u16x8a*)((const unsigned short*)src + off);
    }
}
__device__ __forceinline__ float rdel(const void* p, size_t i, int f) {
    return f ? ((const f32a*)p)[i] : bf2f(((const u16a*)p)[i]);
}
// Async global->LDS, 16 B per lane.  LDS dst is wave-uniform base +
// lane*16 (HW rule); global src is per-lane (enables source pre-swizzle).
__device__ __forceinline__ void gload16(const void* g, void* l) {
    __builtin_amdgcn_global_load_lds(
        (const __attribute__((address_space(1))) unsigned int*)g,
        (__attribute__((address_space(3))) unsigned int*)l,
        16, 0, 0);
}

// ---------------------------------------------------------------------------
// Dtype sniffer: flag = 1 -> fp32 inputs (and fp32 output).
// ---------------------------------------------------------------------------
__global__ void sniff(const void* __restrict__ q, int* __restrict__ flag) {
    __shared__ int cnt;
    if (threadIdx.x == 0) cnt = 0;
    __syncthreads();
    const u16a* p = (const u16a*)q;
    int c = 0;
#pragma unroll
    for (int i = 0; i < 8; i++) {
        unsigned short u = p[threadIdx.x * 8 + i];
        int e = (u >> 7) & 0xFF;
        if (e >= 96 && e <= 159) c++;
    }
    atomicAdd(&cnt, c);
    __syncthreads();
    if (threadIdx.x == 0) *flag = (cnt < 1741) ? 1 : 0;   // 85% of 2048
}

// ---------------------------------------------------------------------------
// Convert pass: fp32 -> bf16.  z 0..2: activations, z 3..6: weights.
// No-op when inputs are already bf16 (flag==0).
// ---------------------------------------------------------------------------
__global__ __launch_bounds__(256)
void convert(const void* s0, const void* s1, const void* s2, const void* s3,
             const void* s4, const void* s5, const void* s6,
             unsigned short* d0, unsigned short* d1, unsigned short* d2,
             unsigned short* d3, unsigned short* d4, unsigned short* d5,
             unsigned short* d6, const int* __restrict__ flag)
{
    if (*flag == 0) return;
    const int z = blockIdx.z;
    const float* s; unsigned short* d; size_t n;
    switch (z) {
        case 0: s = (const float*)s0; d = d0; n = (size_t)BATCH * SQL * DM; break;
        case 1: s = (const float*)s1; d = d1; n = (size_t)BATCH * SQL * DM; break;
        case 2: s = (const float*)s2; d = d2; n = (size_t)BATCH * SQL * DM; break;
        case 3: s = (const float*)s3; d = d3; n = (size_t)DM * DM; break;
        case 4: s = (const float*)s4; d = d4; n = (size_t)DM * DM; break;
        case 5: s = (const float*)s5; d = d5; n = (size_t)DM * DM; break;
        default: s = (const float*)s6; d = d6; n = (size_t)DM * DM; break;
    }
    const size_t stride = (size_t)gridDim.x * blockDim.x * 8;
    for (size_t i = ((size_t)blockIdx.x * blockDim.x + threadIdx.x) * 8; i < n;
         i += stride) {
        f32x8 v = *(const f32x8a*)(s + i);
        u16x8 o;
#pragma unroll
        for (int j = 0; j < 8; j++) o[j] = f2bf(v[j]);
        *(u16x8a*)(d + i) = o;
    }
}

// ---------------------------------------------------------------------------
// GEMM core (m97 structure): C = A[M,K] @ Bt[N,K]^T + bias.  K=N=1024,
// bf16 MFMA 16x16x32, 128x128 tile, BK=32, 4 waves 2x2, 4x4 frags/wave.
// oMode: 0 = bf16 row-major, 1 = f32 row-major, 2 = bf16 VT[b][h][d][tok]
// (packed b64 stores; 4 acc rows per fragment are contiguous toks).
// ---------------------------------------------------------------------------
template<int BLDS>
__device__ __forceinline__ void gemm_core(
    const unsigned short* __restrict__ Abf,
    const unsigned short* __restrict__ Bbf,   // bf16 B (used when BLDS)
    const void* __restrict__ Braw,            // raw B, dtype wF32 (BLDS=0)
    const void* __restrict__ bias, void* __restrict__ Cv,
    float scale, int wF32, int oMode, int bF32)
{
    constexpr int K = 1024, N = 1024, BK = 32;
    __shared__ unsigned short Alds[128 * BK];
    __shared__ unsigned short Blds[128 * BK];

    const int t = threadIdx.x;
    const int lane = t & 63, wave = t >> 6;
    const int quad = lane >> 4, r15 = lane & 15;
    const int wm = (wave >> 1) * 64, wn = (wave & 1) * 64;
    const int m0 = blockIdx.x * 128, n0 = blockIdx.y * 128;

    f32x4 acc[4][4];
#pragma unroll
    for (int i = 0; i < 4; i++)
#pragma unroll
        for (int j = 0; j < 4; j++) acc[i][j] = (f32x4){0.f, 0.f, 0.f, 0.f};

    const int gr = lane >> 2, gc = lane & 3;
    const unsigned short* gA = Abf + (size_t)(m0 + wave * 32 + gr) * K + gc * 8;
    const unsigned short* gB = Bbf + (size_t)(n0 + wave * 32 + gr) * K + gc * 8;
    unsigned short* lA = &Alds[wave * 1024];
    unsigned short* lB = &Blds[wave * 1024];
    const int srow = t >> 2, sch = t & 3;
    const size_t offB0 = (size_t)(n0 + srow) * K + sch * 8;
    const size_t offB1 = (size_t)(n0 + 64 + srow) * K + sch * 8;

    for (int k0 = 0; k0 < K; k0 += BK) {
        gload16(gA + k0, lA);
        gload16(gA + k0 + 16 * K, lA + 512);
        if constexpr (BLDS) {
            gload16(gB + k0, lB);
            gload16(gB + k0 + 16 * K, lB + 512);
        } else {
            stage8(Braw, offB0 + k0, wF32, &Blds[srow * BK + sch * 8]);
            stage8(Braw, offB1 + k0, wF32, &Blds[(64 + srow) * BK + sch * 8]);
        }
        __syncthreads();

        bf16x8 af[4], bfr[4];
#pragma unroll
        for (int i = 0; i < 4; i++)
            af[i] = ldfrag(&Alds[(wm + i * 16 + r15) * BK + quad * 8]);
#pragma unroll
        for (int j = 0; j < 4; j++)
            bfr[j] = ldfrag(&Blds[(wn + j * 16 + r15) * BK + quad * 8]);
#pragma unroll
        for (int i = 0; i < 4; i++)
#pragma unroll
            for (int j = 0; j < 4; j++)
                acc[i][j] = __builtin_amdgcn_mfma_f32_16x16x32_bf16(af[i], bfr[j], acc[i][j], 0, 0, 0);
        __syncthreads();
    }

    float bvv[4];
#pragma unroll
    for (int j = 0; j < 4; j++)
        bvv[j] = rdel(bias, n0 + wn + j * 16 + r15, bF32);

    if (oMode == 2) {
        // VT[b][h][d][tok]: per fragment, 4 acc rows = 4 contiguous toks.
#pragma unroll
        for (int i = 0; i < 4; i++)
#pragma unroll
            for (int j = 0; j < 4; j++) {
                int rr = m0 + wm + i * 16 + quad * 4;
                int cc = n0 + wn + j * 16 + r15;
                int bb = rr >> 11, tok = rr & (SQL - 1);
                int hh = cc >> 6,  dd  = cc & (HD - 1);
                u16x4 pk;
#pragma unroll
                for (int r = 0; r < 4; r++) pk[r] = f2bf(acc[i][j][r] + bvv[j]);
                *(u16x4a*)&((u16a*)Cv)[((((size_t)bb * NH + hh) * HD + dd) << 11) + tok] = pk;
            }
    } else {
#pragma unroll
        for (int i = 0; i < 4; i++)
#pragma unroll
            for (int j = 0; j < 4; j++)
#pragma unroll
                for (int r = 0; r < 4; r++) {
                    int rr = m0 + wm + i * 16 + quad * 4 + r;
                    int cc = n0 + wn + j * 16 + r15;
                    float vv = (acc[i][j][r] + bvv[j]) * scale;
                    if (oMode) ((f32a*)Cv)[(size_t)rr * N + cc] = vv;
                    else       ((u16a*)Cv)[(size_t)rr * N + cc] = f2bf(vv);
                }
    }
}

template<int BLDS>
__global__ __launch_bounds__(256)
void gemm_qkv_k(const void* __restrict__ xq, const void* __restrict__ xk,
                const void* __restrict__ xv,
                const unsigned short* __restrict__ qc,
                const unsigned short* __restrict__ kc,
                const unsigned short* __restrict__ vc,
                const void* __restrict__ Wq, const void* __restrict__ Wk,
                const void* __restrict__ Wv,
                const unsigned short* __restrict__ Wqc,
                const unsigned short* __restrict__ Wkc,
                const unsigned short* __restrict__ Wvc,
                const void* __restrict__ bq, const void* __restrict__ bk,
                const void* __restrict__ bv,
                unsigned short* __restrict__ Qp, unsigned short* __restrict__ Kp,
                unsigned short* __restrict__ Vp,
                float qscale, const int* __restrict__ flag)
{
    const int f = *flag;
    const int z = blockIdx.z;
    const void* xo = (z == 0) ? xq : (z == 1) ? xk : xv;
    const unsigned short* xc = (z == 0) ? qc : (z == 1) ? kc : vc;
    const unsigned short* A = f ? xc : (const unsigned short*)xo;
    const void* Wraw = (z == 0) ? Wq : (z == 1) ? Wk : Wv;
    const unsigned short* Wc = (z == 0) ? Wqc : (z == 1) ? Wkc : Wvc;
    const unsigned short* Bc = (BLDS && f) ? Wc : (const unsigned short*)Wraw;
    const void* bi = (z == 0) ? bq : (z == 1) ? bk : bv;
    unsigned short* C = (z == 0) ? Qp : (z == 1) ? Kp : Vp;
    gemm_core<BLDS>(A, Bc, Wraw, bi, C, (z == 0) ? qscale : 1.0f, f,
                    (z == 2) ? 2 : 0, f);
}

template<int BLDS>
__global__ __launch_bounds__(256)
void gemm_o_k(const unsigned short* __restrict__ A, const void* __restrict__ Wo,
              const unsigned short* __restrict__ Woc, const void* __restrict__ bo,
              void* __restrict__ out, const int* __restrict__ flag)
{
    const int f = *flag;
    const unsigned short* Bc = (BLDS && f) ? Woc : (const unsigned short*)Wo;
    gemm_core<BLDS>(A, Bc, Wo, bo, out, 1.0f, f, f, f);
}

// ---------------------------------------------------------------------------
// Flash attention, maxless softmax, 2-phase async staging.
// Grid (32 q-tiles, 32 b*h), 4 waves; each wave owns 16 Q rows.
// K tile [key][64] and V tile [d][key] (from VT) staged via global_load_lds
// into linear 128B-row LDS with XOR chunk swizzle slot = c ^ (row&7):
// inverse-permuted global source, XOR'd read address.  Double-buffered;
// next tile's loads issue before current tile's compute; one barrier/tile.
// ---------------------------------------------------------------------------
__global__ __launch_bounds__(256)
void flash(const unsigned short* __restrict__ Qp,
           const unsigned short* __restrict__ Kp,
           const unsigned short* __restrict__ VT,
           const int* __restrict__ mask,
           unsigned short* __restrict__ AO)
{
    __shared__ unsigned short Klds[2][64 * 64];   // [key][d], swizzled slots
    __shared__ unsigned short Vlds[2][64 * 64];   // [d][key], swizzled slots
    __shared__ unsigned short Plds[4][16 * 72];   // per-wave P, padded rows

    const int t = threadIdx.x, wave = t >> 6, lane = t & 63;
    const int quad = lane >> 4, r15 = lane & 15;
    const int x7 = r15 & 7;                        // read-side XOR key
    const int qt = blockIdx.x, bh = blockIdx.y, b = bh >> 4, h = bh & 15;
    const size_t base = (size_t)b * SQL * DM + (size_t)h * HD;

    // ---- staging geometry: per wave 2 K-calls + 2 V-calls, 8 rows/call ----
    const int srow8 = lane >> 3, sc8 = lane & 7;
    const unsigned short* gK[2];
    const unsigned short* gV[2];
    int ldof[2];
#pragma unroll
    for (int i = 0; i < 2; i++) {
        const int row = wave * 16 + i * 8 + srow8;     // key (K) / d (V)
        const int slot = sc8 ^ (row & 7);              // inverse swizzle
        gK[i] = Kp + base + (size_t)row * DM + slot * 8;
        gV[i] = VT + (((size_t)(b * NH + h) * HD + row) << 11) + slot * 8;
        ldof[i] = (wave * 16 + i * 8) * 64;            // wave-uniform LDS base
    }

    // ---- Q fragments (row-major read, hoisted) ----
    const int qrow = qt * 64 + wave * 16 + r15;
    const bf16x8 qf0 = ldfrag(&Qp[base + (size_t)qrow * DM + quad * 8]);
    const bf16x8 qf1 = ldfrag(&Qp[base + (size_t)qrow * DM + 32 + quad * 8]);

    f32x4 o[4];
#pragma unroll
    for (int jd = 0; jd < 4; jd++) o[jd] = (f32x4){0.f, 0.f, 0.f, 0.f};
    float l_i[4] = {0.f, 0.f, 0.f, 0.f};

    // ---- prologue: stage tile 0 into buffer 0 ----
#pragma unroll
    for (int i = 0; i < 2; i++) {
        gload16(gK[i], &Klds[0][ldof[i]]);
        gload16(gV[i], &Vlds[0][ldof[i]]);
    }
    __syncthreads();

    constexpr int NT = SQL / 64;
    for (int it = 0; it < NT; ++it) {
        const int bs = it & 1;
        const int n0 = it * 64;

        // mask loads first (so their waits don't drain the prefetch)
        int mraw[4];
#pragma unroll
        for (int j = 0; j < 4; j++)
            mraw[j] = mask[b * SQL + n0 + j * 16 + r15];

        // issue next tile's loads before compute (2-phase async)
        if (it + 1 < NT) {
#pragma unroll
            for (int i = 0; i < 2; i++) {
                gload16(gK[i] + (size_t)(n0 + 64) * DM, &Klds[bs ^ 1][ldof[i]]);
                gload16(gV[i] + (n0 + 64),              &Vlds[bs ^ 1][ldof[i]]);
            }
        }

        // ---- S = Q K^T (log2-scaled); swizzled K reads ----
        f32x4 s4[4];
#pragma unroll
        for (int j = 0; j < 4; j++) s4[j] = (f32x4){0.f, 0.f, 0.f, 0.f};
#pragma unroll
        for (int j = 0; j < 4; j++) {
            const int row = j * 16 + r15;
            bf16x8 kf0 = ldfrag(&Klds[bs][row * 64 + ((quad ^ x7) << 3)]);
            bf16x8 kf1 = ldfrag(&Klds[bs][row * 64 + (((4 + quad) ^ x7) << 3)]);
            s4[j] = __builtin_amdgcn_mfma_f32_16x16x32_bf16(qf0, kf0, s4[j], 0, 0, 0);
            s4[j] = __builtin_amdgcn_mfma_f32_16x16x32_bf16(qf1, kf1, s4[j], 0, 0, 0);
        }

        // ---- maxless softmax: p = exp2(s); masked -> -inf -> p = 0 ----
#pragma unroll
        for (int j = 0; j < 4; j++) {
            const float mval = (mraw[j] != 0) ? -INFINITY : 0.f;
#pragma unroll
            for (int r = 0; r < 4; r++) {
                float p = exp2f(s4[j][r] + mval);
                l_i[r] += p;
                Plds[wave][(quad * 4 + r) * 72 + j * 16 + r15] = f2bf(p);
            }
        }
        // Wave-private P round-trip: DS in-order per wave; compiler fence.
        asm volatile("" ::: "memory");

        // ---- O += P @ V : swizzled V reads ----
#pragma unroll
        for (int kf = 0; kf < 2; kf++) {
            bf16x8 pa = ldfrag(&Plds[wave][r15 * 72 + kf * 32 + quad * 8]);
#pragma unroll
            for (int jd = 0; jd < 4; jd++) {
                const int row = jd * 16 + r15;
                bf16x8 vb8 = ldfrag(
                    &Vlds[bs][row * 64 + (((kf * 4 + quad) ^ x7) << 3)]);
                o[jd] = __builtin_amdgcn_mfma_f32_16x16x32_bf16(pa, vb8, o[jd], 0, 0, 0);
            }
        }
        // single barrier per tile: drains next-tile loads (compiler emits
        // vmcnt(0) here) and protects buffer reuse.
        __syncthreads();
    }

    // ---- one-time l reduction across the 16 lanes of each quad ----
#pragma unroll
    for (int off = 1; off < 16; off <<= 1)
#pragma unroll
        for (int r = 0; r < 4; r++) l_i[r] += __shfl_xor(l_i[r], off, 64);
#pragma unroll
    for (int r = 0; r < 4; r++) l_i[r] = (l_i[r] > 0.f) ? 1.0f / l_i[r] : 0.f;

    // ---- epilogue: O / l -> bf16 ws at (b, row, h*64 + d) ----
#pragma unroll
    for (int jd = 0; jd < 4; jd++)
#pragma unroll
        for (int r = 0; r < 4; r++) {
            int row = qt * 64 + wave * 16 + quad * 4 + r;
            AO[base + (size_t)row * DM + jd * 16 + r15] = f2bf(o[jd][r] * l_i[r]);
        }
}

// ---------------------------------------------------------------------------
extern "C" void kernel_launch(void* const* d_in, const int* in_sizes, int n_in,
                              void* d_out, int out_size, void* d_ws, size_t ws_size,
                              hipStream_t stream)
{
    (void)in_sizes; (void)n_in; (void)out_size;

    const void* q    = d_in[0];
    const void* k    = d_in[1];
    const void* v    = d_in[2];
    const int*  mask = (const int*)d_in[3];
    const void* Wq   = d_in[4];
    const void* bq   = d_in[5];
    const void* Wk   = d_in[6];
    const void* bk   = d_in[7];
    const void* Wv   = d_in[8];
    const void* bv   = d_in[9];
    const void* Wo   = d_in[10];
    const void* bo   = d_in[11];

    const size_t ACT = (size_t)BATCH * SQL * DM;   // 4M elems (8 MB bf16)
    const size_t WE  = (size_t)DM * DM;            // 1M elems (2 MB bf16)
    int* flag = (int*)d_ws;                        // 512 B header
    unsigned short* Qp = (unsigned short*)((char*)d_ws + 512);
    unsigned short* Kp = Qp + ACT;
    unsigned short* Vp = Kp + ACT;                 // holds VT[b][h][d][tok]
    unsigned short* AO = Vp + ACT;                 // 32 MB + 512 B baseline

    const size_t needFull = 512 + (4 * ACT + 3 * ACT + 4 * WE) * 2;
    const size_t needMid  = 512 + (4 * ACT + 4 * WE) * 2;
    const int tier = (ws_size >= needFull) ? 2 : (ws_size >= needMid) ? 1 : 0;

    unsigned short* qc;
    unsigned short* kc;
    unsigned short* vc;
    unsigned short* Wqc = AO + ACT;                // ws past baseline
    unsigned short* Wkc = Wqc + WE;
    unsigned short* Wvc = Wkc + WE;
    unsigned short* Woc = Wvc + WE;
    if (tier == 2) {
        qc = Woc + WE;
        kc = qc + ACT;
        vc = kc + ACT;
    } else {
        qc = AO;                                   // dead until flash writes
        kc = (unsigned short*)d_out;               // dead until gemm_o writes
        vc = kc + ACT;
    }

    // Fold 1/sqrt(64) and log2(e) into Q so flash uses exp2 directly.
    const float QSCALE = 0.125f * 1.44269504088896340736f;

    sniff<<<1, 256, 0, stream>>>(q, flag);
    if (tier >= 1) {
        convert<<<dim3(256, 1, 7), 256, 0, stream>>>(
            q, k, v, Wq, Wk, Wv, Wo, qc, kc, vc, Wqc, Wkc, Wvc, Woc, flag);
        gemm_qkv_k<1><<<dim3(32, 8, 3), 256, 0, stream>>>(
            q, k, v, qc, kc, vc, Wq, Wk, Wv, Wqc, Wkc, Wvc,
            bq, bk, bv, Qp, Kp, Vp, QSCALE, flag);
    } else {
        convert<<<dim3(256, 1, 3), 256, 0, stream>>>(
            q, k, v, nullptr, nullptr, nullptr, nullptr,
            qc, kc, vc, nullptr, nullptr, nullptr, nullptr, flag);
        gemm_qkv_k<0><<<dim3(32, 8, 3), 256, 0, stream>>>(
            q, k, v, qc, kc, vc, Wq, Wk, Wv, nullptr, nullptr, nullptr,
            bq, bk, bv, Qp, Kp, Vp, QSCALE, flag);
    }
    flash<<<dim3(SQL / 64, BATCH * NH), 256, 0, stream>>>(Qp, Kp, Vp, mask, AO);
    if (tier >= 1)
        gemm_o_k<1><<<dim3(32, 8), 256, 0, stream>>>(AO, Wo, Woc, bo, d_out, flag);
    else
        gemm_o_k<0><<<dim3(32, 8), 256, 0, stream>>>(AO, Wo, nullptr, bo, d_out, flag);
}

// Round 5
// 254.984 us; speedup vs baseline: 1.3226x; 1.1100x over previous
//
#include <hip/hip_runtime.h>
#include <hip/hip_bf16.h>
#include <math.h>
#include <stdint.h>

// ---------------------------------------------------------------------------
// AttentionLayer B=2,S=2048,D=1024,H=16,Hd=64.  fp32 or bf16 in/out, sniffed
// at runtime.  Pipeline: sniff -> convert -> gemm_qkv -> flash -> gemm_o.
// R14 (= R13 resubmit after container flake; audited for hangs/faults:
// uniform barriers only, LDS 50KB, all indices in bounds, aligned stores):
//  * flash: each wave owns 32 q-rows (2 x 16-row groups), 128 q-rows/block,
//    grid (16,32)=512 blocks.  K/V fragments + staging + mask loads are
//    amortized over 2x the q-rows: 32 MFMA against 20 ds_read_b128 per tile
//    (was 16 against 18).  Keeps R12's XOR-swizzled global_load_lds staging
//    and 2-phase double buffering.
//  * gemm_o: 128x64 tile -> 512 blocks = 2 blocks/CU (was 256 = 1/CU; the
//    2-barrier m97 loop needs cross-block wave overlap to hide the barrier
//    drain).  gemm_core templated on BN; qkv stays 128x128 (3/CU via z=3).
// ---------------------------------------------------------------------------

typedef __bf16 bf16x8 __attribute__((ext_vector_type(8)));
typedef float  f32x4  __attribute__((ext_vector_type(4)));
typedef float  f32x8  __attribute__((ext_vector_type(8)));
typedef unsigned short u16x8 __attribute__((ext_vector_type(8)));
typedef unsigned short u16x4 __attribute__((ext_vector_type(4)));
typedef u16x8 u16x8a __attribute__((may_alias));
typedef u16x4 u16x4a __attribute__((may_alias));
typedef f32x8 f32x8a __attribute__((may_alias));
typedef unsigned short u16a __attribute__((may_alias));
typedef float f32a __attribute__((may_alias));

#define BATCH 2
#define SQL   2048
#define DM    1024
#define NH    16
#define HD    64

__device__ __forceinline__ unsigned short f2bf(float f) {
    union { __hip_bfloat16 h; unsigned short u; } cv;
    cv.h = __float2bfloat16(f);
    return cv.u;
}
__device__ __forceinline__ float bf2f(unsigned short u) {
    union { unsigned int i; float f; } cv;
    cv.i = ((unsigned int)u) << 16;
    return cv.f;
}
__device__ __forceinline__ bf16x8 ldfrag(const unsigned short* p) {
    return __builtin_bit_cast(bf16x8, *(const u16x8a*)p);
}
__device__ __forceinline__ void stage8(const void* __restrict__ src, size_t off,
                                       int f32f, unsigned short* dst) {
    if (f32f) {
        f32x8 v = *(const f32x8a*)((const float*)src + off);
        u16x8 o;
#pragma unroll
        for (int i = 0; i < 8; i++) o[i] = f2bf(v[i]);
        *(u16x8a*)dst = o;
    } else {
        *(u16x8a*)dst = *(const u16x8a*)((const unsigned short*)src + off);
    }
}
__device__ __forceinline__ float rdel(const void* p, size_t i, int f) {
    return f ? ((const f32a*)p)[i] : bf2f(((const u16a*)p)[i]);
}
// Async global->LDS, 16 B per lane.  LDS dst is wave-uniform base +
// lane*16 (HW rule); global src is per-lane (enables source pre-swizzle).
__device__ __forceinline__ void gload16(const void* g, void* l) {
    __builtin_amdgcn_global_load_lds(
        (const __attribute__((address_space(1))) unsigned int*)g,
        (__attribute__((address_space(3))) unsigned int*)l,
        16, 0, 0);
}

// ---------------------------------------------------------------------------
// Dtype sniffer: flag = 1 -> fp32 inputs (and fp32 output).
// ---------------------------------------------------------------------------
__global__ void sniff(const void* __restrict__ q, int* __restrict__ flag) {
    __shared__ int cnt;
    if (threadIdx.x == 0) cnt = 0;
    __syncthreads();
    const u16a* p = (const u16a*)q;
    int c = 0;
#pragma unroll
    for (int i = 0; i < 8; i++) {
        unsigned short u = p[threadIdx.x * 8 + i];
        int e = (u >> 7) & 0xFF;
        if (e >= 96 && e <= 159) c++;
    }
    atomicAdd(&cnt, c);
    __syncthreads();
    if (threadIdx.x == 0) *flag = (cnt < 1741) ? 1 : 0;   // 85% of 2048
}

// ---------------------------------------------------------------------------
// Convert pass: fp32 -> bf16.  z 0..2: activations, z 3..6: weights.
// No-op when inputs are already bf16 (flag==0).
// ---------------------------------------------------------------------------
__global__ __launch_bounds__(256)
void convert(const void* s0, const void* s1, const void* s2, const void* s3,
             const void* s4, const void* s5, const void* s6,
             unsigned short* d0, unsigned short* d1, unsigned short* d2,
             unsigned short* d3, unsigned short* d4, unsigned short* d5,
             unsigned short* d6, const int* __restrict__ flag)
{
    if (*flag == 0) return;
    const int z = blockIdx.z;
    const float* s; unsigned short* d; size_t n;
    switch (z) {
        case 0: s = (const float*)s0; d = d0; n = (size_t)BATCH * SQL * DM; break;
        case 1: s = (const float*)s1; d = d1; n = (size_t)BATCH * SQL * DM; break;
        case 2: s = (const float*)s2; d = d2; n = (size_t)BATCH * SQL * DM; break;
        case 3: s = (const float*)s3; d = d3; n = (size_t)DM * DM; break;
        case 4: s = (const float*)s4; d = d4; n = (size_t)DM * DM; break;
        case 5: s = (const float*)s5; d = d5; n = (size_t)DM * DM; break;
        default: s = (const float*)s6; d = d6; n = (size_t)DM * DM; break;
    }
    const size_t stride = (size_t)gridDim.x * blockDim.x * 8;
    for (size_t i = ((size_t)blockIdx.x * blockDim.x + threadIdx.x) * 8; i < n;
         i += stride) {
        f32x8 v = *(const f32x8a*)(s + i);
        u16x8 o;
#pragma unroll
        for (int j = 0; j < 8; j++) o[j] = f2bf(v[j]);
        *(u16x8a*)(d + i) = o;
    }
}

// ---------------------------------------------------------------------------
// GEMM core (m97 structure): C = A[M,K] @ Bt[N,K]^T + bias.  K=N=1024,
// bf16 MFMA 16x16x32, 128xBN tile (BN = 128 or 64), BK=32, 4 waves 2x2,
// 4xNJ frags/wave (NJ = BN/32).
// oMode: 0 = bf16 row-major, 1 = f32 row-major, 2 = bf16 VT[b][h][d][tok]
// (packed b64 stores; 4 acc rows per fragment are contiguous toks).
// ---------------------------------------------------------------------------
template<int BLDS, int BN>
__device__ __forceinline__ void gemm_core(
    const unsigned short* __restrict__ Abf,
    const unsigned short* __restrict__ Bbf,   // bf16 B (used when BLDS)
    const void* __restrict__ Braw,            // raw B, dtype wF32 (BLDS=0)
    const void* __restrict__ bias, void* __restrict__ Cv,
    float scale, int wF32, int oMode, int bF32)
{
    constexpr int K = 1024, N = 1024, BK = 32;
    constexpr int NJ = BN / 32;               // B frags per wave
    constexpr int CALLS = BN / 64;            // B gload16 calls per wave
    __shared__ unsigned short Alds[128 * BK];
    __shared__ unsigned short Blds[BN * BK];

    const int t = threadIdx.x;
    const int lane = t & 63, wave = t >> 6;
    const int quad = lane >> 4, r15 = lane & 15;
    const int wm = (wave >> 1) * 64, wn = (wave & 1) * (BN / 2);
    const int m0 = blockIdx.x * 128, n0 = blockIdx.y * BN;

    f32x4 acc[4][NJ];
#pragma unroll
    for (int i = 0; i < 4; i++)
#pragma unroll
        for (int j = 0; j < NJ; j++) acc[i][j] = (f32x4){0.f, 0.f, 0.f, 0.f};

    const int gr = lane >> 2, gc = lane & 3;
    const unsigned short* gA = Abf + (size_t)(m0 + wave * 32 + gr) * K + gc * 8;
    const unsigned short* gB = Bbf + (size_t)(n0 + wave * 16 * CALLS + gr) * K + gc * 8;
    unsigned short* lA = &Alds[wave * 1024];
    unsigned short* lB = &Blds[wave * 512 * CALLS];
    const int srow = t >> 2, sch = t & 3;
    const size_t offB0 = (size_t)(n0 + srow) * K + sch * 8;
    const size_t offB1 = (size_t)(n0 + 64 + srow) * K + sch * 8;

    for (int k0 = 0; k0 < K; k0 += BK) {
        gload16(gA + k0, lA);
        gload16(gA + k0 + 16 * K, lA + 512);
        if constexpr (BLDS) {
#pragma unroll
            for (int c = 0; c < CALLS; c++)
                gload16(gB + k0 + c * 16 * K, lB + c * 512);
        } else {
            stage8(Braw, offB0 + k0, wF32, &Blds[srow * BK + sch * 8]);
            if constexpr (BN == 128)
                stage8(Braw, offB1 + k0, wF32, &Blds[(64 + srow) * BK + sch * 8]);
        }
        __syncthreads();

        bf16x8 af[4], bfr[NJ];
#pragma unroll
        for (int i = 0; i < 4; i++)
            af[i] = ldfrag(&Alds[(wm + i * 16 + r15) * BK + quad * 8]);
#pragma unroll
        for (int j = 0; j < NJ; j++)
            bfr[j] = ldfrag(&Blds[(wn + j * 16 + r15) * BK + quad * 8]);
#pragma unroll
        for (int i = 0; i < 4; i++)
#pragma unroll
            for (int j = 0; j < NJ; j++)
                acc[i][j] = __builtin_amdgcn_mfma_f32_16x16x32_bf16(af[i], bfr[j], acc[i][j], 0, 0, 0);
        __syncthreads();
    }

    float bvv[NJ];
#pragma unroll
    for (int j = 0; j < NJ; j++)
        bvv[j] = rdel(bias, n0 + wn + j * 16 + r15, bF32);

    if (oMode == 2) {
        // VT[b][h][d][tok]: per fragment, 4 acc rows = 4 contiguous toks.
#pragma unroll
        for (int i = 0; i < 4; i++)
#pragma unroll
            for (int j = 0; j < NJ; j++) {
                int rr = m0 + wm + i * 16 + quad * 4;
                int cc = n0 + wn + j * 16 + r15;
                int bb = rr >> 11, tok = rr & (SQL - 1);
                int hh = cc >> 6,  dd  = cc & (HD - 1);
                u16x4 pk;
#pragma unroll
                for (int r = 0; r < 4; r++) pk[r] = f2bf(acc[i][j][r] + bvv[j]);
                *(u16x4a*)&((u16a*)Cv)[((((size_t)bb * NH + hh) * HD + dd) << 11) + tok] = pk;
            }
    } else {
#pragma unroll
        for (int i = 0; i < 4; i++)
#pragma unroll
            for (int j = 0; j < NJ; j++)
#pragma unroll
                for (int r = 0; r < 4; r++) {
                    int rr = m0 + wm + i * 16 + quad * 4 + r;
                    int cc = n0 + wn + j * 16 + r15;
                    float vv = (acc[i][j][r] + bvv[j]) * scale;
                    if (oMode) ((f32a*)Cv)[(size_t)rr * N + cc] = vv;
                    else       ((u16a*)Cv)[(size_t)rr * N + cc] = f2bf(vv);
                }
    }
}

template<int BLDS>
__global__ __launch_bounds__(256)
void gemm_qkv_k(const void* __restrict__ xq, const void* __restrict__ xk,
                const void* __restrict__ xv,
                const unsigned short* __restrict__ qc,
                const unsigned short* __restrict__ kc,
                const unsigned short* __restrict__ vc,
                const void* __restrict__ Wq, const void* __restrict__ Wk,
                const void* __restrict__ Wv,
                const unsigned short* __restrict__ Wqc,
                const unsigned short* __restrict__ Wkc,
                const unsigned short* __restrict__ Wvc,
                const void* __restrict__ bq, const void* __restrict__ bk,
                const void* __restrict__ bv,
                unsigned short* __restrict__ Qp, unsigned short* __restrict__ Kp,
                unsigned short* __restrict__ Vp,
                float qscale, const int* __restrict__ flag)
{
    const int f = *flag;
    const int z = blockIdx.z;
    const void* xo = (z == 0) ? xq : (z == 1) ? xk : xv;
    const unsigned short* xc = (z == 0) ? qc : (z == 1) ? kc : vc;
    const unsigned short* A = f ? xc : (const unsigned short*)xo;
    const void* Wraw = (z == 0) ? Wq : (z == 1) ? Wk : Wv;
    const unsigned short* Wc = (z == 0) ? Wqc : (z == 1) ? Wkc : Wvc;
    const unsigned short* Bc = (BLDS && f) ? Wc : (const unsigned short*)Wraw;
    const void* bi = (z == 0) ? bq : (z == 1) ? bk : bv;
    unsigned short* C = (z == 0) ? Qp : (z == 1) ? Kp : Vp;
    gemm_core<BLDS, 128>(A, Bc, Wraw, bi, C, (z == 0) ? qscale : 1.0f, f,
                         (z == 2) ? 2 : 0, f);
}

template<int BLDS>
__global__ __launch_bounds__(256)
void gemm_o_k(const unsigned short* __restrict__ A, const void* __restrict__ Wo,
              const unsigned short* __restrict__ Woc, const void* __restrict__ bo,
              void* __restrict__ out, const int* __restrict__ flag)
{
    const int f = *flag;
    const unsigned short* Bc = (BLDS && f) ? Woc : (const unsigned short*)Wo;
    gemm_core<BLDS, 64>(A, Bc, Wo, bo, out, 1.0f, f, f, f);
}

// ---------------------------------------------------------------------------
// Flash attention, maxless softmax, 2-phase async staging.
// Grid (16 q-tiles, 32 b*h), 4 waves; each wave owns 32 Q rows (2 groups of
// 16), so K/V fragments, staging, and mask loads amortize over 2x rows.
// K tile [key][64] and V tile [d][key] (from VT) staged via global_load_lds
// with XOR chunk swizzle slot = c ^ (row&7); double-buffered; next tile's
// loads issue before current tile's compute; one barrier/tile.
// ---------------------------------------------------------------------------
__global__ __launch_bounds__(256)
void flash(const unsigned short* __restrict__ Qp,
           const unsigned short* __restrict__ Kp,
           const unsigned short* __restrict__ VT,
           const int* __restrict__ mask,
           unsigned short* __restrict__ AO)
{
    __shared__ unsigned short Klds[2][64 * 64];   // [key][d], swizzled slots
    __shared__ unsigned short Vlds[2][64 * 64];   // [d][key], swizzled slots
    __shared__ unsigned short Plds[4][32 * 72];   // per-wave P, padded rows

    const int t = threadIdx.x, wave = t >> 6, lane = t & 63;
    const int quad = lane >> 4, r15 = lane & 15;
    const int x7 = r15 & 7;                        // read-side XOR key
    const int qt = blockIdx.x, bh = blockIdx.y, b = bh >> 4, h = bh & 15;
    const size_t base = (size_t)b * SQL * DM + (size_t)h * HD;

    // ---- staging geometry: per wave 2 K-calls + 2 V-calls, 8 rows/call ----
    const int srow8 = lane >> 3, sc8 = lane & 7;
    const unsigned short* gK[2];
    const unsigned short* gV[2];
    int ldof[2];
#pragma unroll
    for (int i = 0; i < 2; i++) {
        const int row = wave * 16 + i * 8 + srow8;     // key (K) / d (V)
        const int slot = sc8 ^ (row & 7);              // inverse swizzle
        gK[i] = Kp + base + (size_t)row * DM + slot * 8;
        gV[i] = VT + (((size_t)(b * NH + h) * HD + row) << 11) + slot * 8;
        ldof[i] = (wave * 16 + i * 8) * 64;            // wave-uniform LDS base
    }

    // ---- Q fragments: 2 groups of 16 rows per wave, hoisted ----
    bf16x8 qf[2][2];
#pragma unroll
    for (int g = 0; g < 2; g++) {
        const int qrow = qt * 128 + wave * 32 + g * 16 + r15;
        qf[g][0] = ldfrag(&Qp[base + (size_t)qrow * DM + quad * 8]);
        qf[g][1] = ldfrag(&Qp[base + (size_t)qrow * DM + 32 + quad * 8]);
    }

    f32x4 o[2][4];
#pragma unroll
    for (int g = 0; g < 2; g++)
#pragma unroll
        for (int jd = 0; jd < 4; jd++) o[g][jd] = (f32x4){0.f, 0.f, 0.f, 0.f};
    float l_i[2][4] = {{0.f, 0.f, 0.f, 0.f}, {0.f, 0.f, 0.f, 0.f}};

    // ---- prologue: stage tile 0 into buffer 0 ----
#pragma unroll
    for (int i = 0; i < 2; i++) {
        gload16(gK[i], &Klds[0][ldof[i]]);
        gload16(gV[i], &Vlds[0][ldof[i]]);
    }
    __syncthreads();

    constexpr int NT = SQL / 64;
    for (int it = 0; it < NT; ++it) {
        const int bs = it & 1;
        const int n0 = it * 64;

        // mask loads first (so their waits don't drain the prefetch)
        int mraw[4];
#pragma unroll
        for (int j = 0; j < 4; j++)
            mraw[j] = mask[b * SQL + n0 + j * 16 + r15];

        // issue next tile's loads before compute (2-phase async)
        if (it + 1 < NT) {
#pragma unroll
            for (int i = 0; i < 2; i++) {
                gload16(gK[i] + (size_t)(n0 + 64) * DM, &Klds[bs ^ 1][ldof[i]]);
                gload16(gV[i] + (n0 + 64),              &Vlds[bs ^ 1][ldof[i]]);
            }
        }

        // ---- S = Q K^T (log2-scaled); K frags shared across both groups ----
        f32x4 s4[2][4];
#pragma unroll
        for (int g = 0; g < 2; g++)
#pragma unroll
            for (int j = 0; j < 4; j++) s4[g][j] = (f32x4){0.f, 0.f, 0.f, 0.f};
#pragma unroll
        for (int j = 0; j < 4; j++) {
            const int row = j * 16 + r15;
            bf16x8 kf0 = ldfrag(&Klds[bs][row * 64 + ((quad ^ x7) << 3)]);
            bf16x8 kf1 = ldfrag(&Klds[bs][row * 64 + (((4 + quad) ^ x7) << 3)]);
#pragma unroll
            for (int g = 0; g < 2; g++) {
                s4[g][j] = __builtin_amdgcn_mfma_f32_16x16x32_bf16(qf[g][0], kf0, s4[g][j], 0, 0, 0);
                s4[g][j] = __builtin_amdgcn_mfma_f32_16x16x32_bf16(qf[g][1], kf1, s4[g][j], 0, 0, 0);
            }
        }

        // ---- maxless softmax: p = exp2(s); masked -> -inf -> p = 0 ----
#pragma unroll
        for (int j = 0; j < 4; j++) {
            const float mval = (mraw[j] != 0) ? -INFINITY : 0.f;
#pragma unroll
            for (int g = 0; g < 2; g++)
#pragma unroll
                for (int r = 0; r < 4; r++) {
                    float p = exp2f(s4[g][j][r] + mval);
                    l_i[g][r] += p;
                    Plds[wave][(g * 16 + quad * 4 + r) * 72 + j * 16 + r15] = f2bf(p);
                }
        }
        // Wave-private P round-trip: DS in-order per wave; compiler fence.
        asm volatile("" ::: "memory");

        // ---- O += P @ V : V frags shared across both groups ----
#pragma unroll
        for (int kf = 0; kf < 2; kf++) {
            bf16x8 pa0 = ldfrag(&Plds[wave][(r15) * 72 + kf * 32 + quad * 8]);
            bf16x8 pa1 = ldfrag(&Plds[wave][(16 + r15) * 72 + kf * 32 + quad * 8]);
#pragma unroll
            for (int jd = 0; jd < 4; jd++) {
                const int row = jd * 16 + r15;
                bf16x8 vb8 = ldfrag(
                    &Vlds[bs][row * 64 + (((kf * 4 + quad) ^ x7) << 3)]);
                o[0][jd] = __builtin_amdgcn_mfma_f32_16x16x32_bf16(pa0, vb8, o[0][jd], 0, 0, 0);
                o[1][jd] = __builtin_amdgcn_mfma_f32_16x16x32_bf16(pa1, vb8, o[1][jd], 0, 0, 0);
            }
        }
        // single barrier per tile: drains next-tile loads (compiler emits
        // vmcnt(0) here) and protects buffer reuse.
        __syncthreads();
    }

    // ---- one-time l reduction across the 16 lanes of each quad ----
#pragma unroll
    for (int off = 1; off < 16; off <<= 1)
#pragma unroll
        for (int g = 0; g < 2; g++)
#pragma unroll
            for (int r = 0; r < 4; r++)
                l_i[g][r] += __shfl_xor(l_i[g][r], off, 64);
#pragma unroll
    for (int g = 0; g < 2; g++)
#pragma unroll
        for (int r = 0; r < 4; r++)
            l_i[g][r] = (l_i[g][r] > 0.f) ? 1.0f / l_i[g][r] : 0.f;

    // ---- epilogue: O / l -> bf16 ws at (b, row, h*64 + d) ----
#pragma unroll
    for (int g = 0; g < 2; g++)
#pragma unroll
        for (int jd = 0; jd < 4; jd++)
#pragma unroll
            for (int r = 0; r < 4; r++) {
                int row = qt * 128 + wave * 32 + g * 16 + quad * 4 + r;
                AO[base + (size_t)row * DM + jd * 16 + r15] =
                    f2bf(o[g][jd][r] * l_i[g][r]);
            }
}

// ---------------------------------------------------------------------------
extern "C" void kernel_launch(void* const* d_in, const int* in_sizes, int n_in,
                              void* d_out, int out_size, void* d_ws, size_t ws_size,
                              hipStream_t stream)
{
    (void)in_sizes; (void)n_in; (void)out_size;

    const void* q    = d_in[0];
    const void* k    = d_in[1];
    const void* v    = d_in[2];
    const int*  mask = (const int*)d_in[3];
    const void* Wq   = d_in[4];
    const void* bq   = d_in[5];
    const void* Wk   = d_in[6];
    const void* bk   = d_in[7];
    const void* Wv   = d_in[8];
    const void* bv   = d_in[9];
    const void* Wo   = d_in[10];
    const void* bo   = d_in[11];

    const size_t ACT = (size_t)BATCH * SQL * DM;   // 4M elems (8 MB bf16)
    const size_t WE  = (size_t)DM * DM;            // 1M elems (2 MB bf16)
    int* flag = (int*)d_ws;                        // 512 B header
    unsigned short* Qp = (unsigned short*)((char*)d_ws + 512);
    unsigned short* Kp = Qp + ACT;
    unsigned short* Vp = Kp + ACT;                 // holds VT[b][h][d][tok]
    unsigned short* AO = Vp + ACT;                 // 32 MB + 512 B baseline

    const size_t needFull = 512 + (4 * ACT + 3 * ACT + 4 * WE) * 2;
    const size_t needMid  = 512 + (4 * ACT + 4 * WE) * 2;
    const int tier = (ws_size >= needFull) ? 2 : (ws_size >= needMid) ? 1 : 0;

    unsigned short* qc;
    unsigned short* kc;
    unsigned short* vc;
    unsigned short* Wqc = AO + ACT;                // ws past baseline
    unsigned short* Wkc = Wqc + WE;
    unsigned short* Wvc = Wkc + WE;
    unsigned short* Woc = Wvc + WE;
    if (tier == 2) {
        qc = Woc + WE;
        kc = qc + ACT;
        vc = kc + ACT;
    } else {
        qc = AO;                                   // dead until flash writes
        kc = (unsigned short*)d_out;               // dead until gemm_o writes
        vc = kc + ACT;
    }

    // Fold 1/sqrt(64) and log2(e) into Q so flash uses exp2 directly.
    const float QSCALE = 0.125f * 1.44269504088896340736f;

    sniff<<<1, 256, 0, stream>>>(q, flag);
    if (tier >= 1) {
        convert<<<dim3(256, 1, 7), 256, 0, stream>>>(
            q, k, v, Wq, Wk, Wv, Wo, qc, kc, vc, Wqc, Wkc, Wvc, Woc, flag);
        gemm_qkv_k<1><<<dim3(32, 8, 3), 256, 0, stream>>>(
            q, k, v, qc, kc, vc, Wq, Wk, Wv, Wqc, Wkc, Wvc,
            bq, bk, bv, Qp, Kp, Vp, QSCALE, flag);
    } else {
        convert<<<dim3(256, 1, 3), 256, 0, stream>>>(
            q, k, v, nullptr, nullptr, nullptr, nullptr,
            qc, kc, vc, nullptr, nullptr, nullptr, nullptr, flag);
        gemm_qkv_k<0><<<dim3(32, 8, 3), 256, 0, stream>>>(
            q, k, v, qc, kc, vc, Wq, Wk, Wv, nullptr, nullptr, nullptr,
            bq, bk, bv, Qp, Kp, Vp, QSCALE, flag);
    }
    flash<<<dim3(SQL / 128, BATCH * NH), 256, 0, stream>>>(Qp, Kp, Vp, mask, AO);
    if (tier >= 1)
        gemm_o_k<1><<<dim3(32, 16), 256, 0, stream>>>(AO, Wo, Woc, bo, d_out, flag);
    else
        gemm_o_k<0><<<dim3(32, 16), 256, 0, stream>>>(AO, Wo, nullptr, bo, d_out, flag);
}